// Round 5
// baseline (1857.781 us; speedup 1.0000x reference)
//
#include <hip/hip_runtime.h>

typedef unsigned int uint;
typedef unsigned long long ull;

#define USER_NUM   100000
#define ITEM_NUM   50000
#define N_NODES    (USER_NUM + ITEM_NUM)
#define NNZ        4800000
#define EMB        64
#define EPS_F      0.2f
#define NORM_EPS_F 1e-12f

// buckets of 256 rows
#define RB_SHIFT   8
#define RB         256
#define NB         ((N_NODES + RB - 1) / RB)     // 586
#define CAP        9216                           // mean 8191, std ~90 -> +11 sigma
#define BINA_CHUNK 8192
#define BINA_GRID  ((NNZ + BINA_CHUNK - 1) / BINA_CHUNK)  // 586

// column chunking for spmm L2 locality: 32768 rows * 128 B = 4 MB = one XCD L2
#define CSHIFT     15
#define NCHUNK     5                              // ceil(150000 / 32768)
#define NKEY       2048                           // 256 rows * 8 chunk slots
#define RPW        25                             // rows per wave
#define SPMM_BLOCKS 1500                          // 1500*4*25 = 150000 rows exactly
#define BAR_STRIDE 256                            // ints per barrier (16 ctr * 16 ints)
#define NBAR       15                             // 5 per layer * 3 layers

// ---------------- bf16 helpers ----------------
__device__ inline float bflo(uint u) { return __uint_as_float(u << 16); }
__device__ inline float bfhi(uint u) { return __uint_as_float(u & 0xffff0000u); }
__device__ inline uint f2bf(float f) {                 // RNE round to bf16
    uint u = __float_as_uint(f);
    return (u + 0x7fffu + ((u >> 16) & 1u)) >> 16;
}
__device__ inline uint pack2(float a, float b) { return f2bf(a) | (f2bf(b) << 16); }

// ---------------- CSR build ----------------

__global__ void init_all(int* __restrict__ g, int* __restrict__ bar) {
    int i = blockIdx.x * blockDim.x + threadIdx.x;
    if (i < NB) g[i] = i * CAP;
    if (i < NBAR * BAR_STRIDE) bar[i] = 0;
}

// Phase A: block-level LDS counting sort by bucket; bid array for copy-out.
// Sequential copy-out -> coalesced full-line global writes.
__global__ __launch_bounds__(1024) void binA_kernel(const int* __restrict__ rows,
                                                    const int* __restrict__ cols,
                                                    const float* __restrict__ vals,
                                                    int* __restrict__ gcursor,
                                                    int2* __restrict__ staging) {
    __shared__ int2 data[BINA_CHUNK];            // 64 KB
    __shared__ unsigned short bid[BINA_CHUNK];   // 16 KB
    __shared__ int hist[NB];
    __shared__ int rstart[NB + 1];
    __shared__ int gbase[NB];
    __shared__ int lcur[NB];
    __shared__ int wsum[16];
    int t = threadIdx.x;
    int cbeg = blockIdx.x * BINA_CHUNK;
    int cend = min(cbeg + BINA_CHUNK, NNZ);
    int total = cend - cbeg;

    int r[8];
    if (t < NB) hist[t] = 0;
    __syncthreads();
#pragma unroll
    for (int k = 0; k < 8; ++k) {
        int i = cbeg + (k << 10) + t;
        r[k] = (i < cend) ? rows[i] : -1;
        if (r[k] >= 0) atomicAdd(&hist[r[k] >> RB_SHIFT], 1);
    }
    __syncthreads();

    // 2-barrier hierarchical shfl scan of hist -> exclusive run starts
    int v = (t < NB) ? hist[t] : 0;
    int sc = v;
#pragma unroll
    for (int off = 1; off < 64; off <<= 1) {
        int u = __shfl_up(sc, off, 64);
        if ((t & 63) >= off) sc += u;
    }
    if ((t & 63) == 63) wsum[t >> 6] = sc;
    __syncthreads();
    if (t < 64) {
        int ws = (t < 16) ? wsum[t] : 0;
#pragma unroll
        for (int off = 1; off < 16; off <<= 1) {
            int u = __shfl_up(ws, off, 64);
            if (t >= off) ws += u;
        }
        if (t < 16) wsum[t] = ws;
    }
    __syncthreads();
    int wid = t >> 6;
    int excl = sc - v + ((wid > 0) ? wsum[wid - 1] : 0);
    if (t <= NB) rstart[t] = excl;            // rstart[NB] == total
    if (t < NB) {
        gbase[t] = atomicAdd(&gcursor[t], hist[t]);   // one global atomic per bucket
        lcur[t] = 0;
    }
    __syncthreads();

    // sort into LDS by bucket, recording bucket id per slot
#pragma unroll
    for (int k = 0; k < 8; ++k) {
        if (r[k] >= 0) {
            int i = cbeg + (k << 10) + t;
            int b = r[k] >> RB_SHIFT;
            int pos = rstart[b] + atomicAdd(&lcur[b], 1);
            data[pos] = make_int2(((r[k] & (RB - 1)) << 18) | cols[i],
                                  __float_as_int(vals[i]));
            bid[pos] = (unsigned short)b;
        }
    }
    __syncthreads();

    // sequential copy-out: consecutive threads -> consecutive global addresses
    for (int i = t; i < total; i += 1024) {
        int b = bid[i];
        staging[(long)gbase[b] + (i - rstart[b])] = data[i];
    }
}

// exclusive scan of bucket counts -> bucket_base; sentinel row_ptr[N_NODES]
__global__ __launch_bounds__(1024) void bscan_kernel(const int* __restrict__ gcursor,
                                                     int* __restrict__ bucket_base,
                                                     int* __restrict__ row_ptr) {
    __shared__ int wsum[16];
    int t = threadIdx.x;
    int c = (t < NB) ? (gcursor[t] - t * CAP) : 0;
    int sc = c;
#pragma unroll
    for (int off = 1; off < 64; off <<= 1) {
        int u = __shfl_up(sc, off, 64);
        if ((t & 63) >= off) sc += u;
    }
    if ((t & 63) == 63) wsum[t >> 6] = sc;
    __syncthreads();
    if (t < 64) {
        int ws = (t < 16) ? wsum[t] : 0;
#pragma unroll
        for (int off = 1; off < 16; off <<= 1) {
            int u = __shfl_up(ws, off, 64);
            if (t >= off) ws += u;
        }
        if (t < 16) wsum[t] = ws;
    }
    __syncthreads();
    int wid = t >> 6;
    int excl = sc - c + ((wid > 0) ? wsum[wid - 1] : 0);
    if (t < NB) bucket_base[t] = excl;
    if (t == 0) row_ptr[N_NODES] = NNZ;
}

// Phase B: one 1024-thread block per 256-row bucket. Counting sort by key
// (row_local<<3)|col_chunk == (e.x >> 15). Also PERSISTS per-row chunk
// boundaries (seg[row], relative to row start) straight from the scan, so
// spmm needs no per-row ballot precompute (round-4 version re-read all of
// edges for that). Sequential copy-out keeps line-dense global writes.
__global__ __launch_bounds__(1024) void binB_kernel(const int* __restrict__ gcursor,
                                                    const int* __restrict__ bucket_base,
                                                    const int2* __restrict__ staging,
                                                    int2* __restrict__ edges,
                                                    int* __restrict__ row_ptr,
                                                    ushort4* __restrict__ seg) {
    __shared__ int2 sorted[CAP];      // 72 KB
    __shared__ int s[NKEY];           // 8 KB
    __shared__ int cur[NKEY];         // 8 KB
    __shared__ int wsum[16];
    int b = blockIdx.x;
    int t = threadIdx.x;
    int cnt = gcursor[b] - b * CAP;
    long sbase = (long)b * CAP;
    int base = bucket_base[b];

    s[t] = 0;
    s[t + 1024] = 0;
    __syncthreads();
    // pass 1: histogram by (row_local, chunk) key
    for (int i = t; i < cnt; i += 1024)
        atomicAdd(&s[((unsigned)staging[sbase + i].x) >> 15], 1);
    __syncthreads();

    // scan 2048 keys: pair-per-thread + hierarchical shfl scan
    int v0 = s[2 * t], v1 = s[2 * t + 1];
    int pv = v0 + v1;
    int sc = pv;
#pragma unroll
    for (int off = 1; off < 64; off <<= 1) {
        int u = __shfl_up(sc, off, 64);
        if ((t & 63) >= off) sc += u;
    }
    if ((t & 63) == 63) wsum[t >> 6] = sc;
    __syncthreads();
    if (t < 64) {
        int ws = (t < 16) ? wsum[t] : 0;
#pragma unroll
        for (int off = 1; off < 16; off <<= 1) {
            int u = __shfl_up(ws, off, 64);
            if (t >= off) ws += u;
        }
        if (t < 16) wsum[t] = ws;
    }
    __syncthreads();
    int wid = t >> 6;
    int ex = sc - pv + ((wid > 0) ? wsum[wid - 1] : 0);
    cur[2 * t] = ex;
    cur[2 * t + 1] = ex + v0;
    __syncthreads();

    if (t < RB) {
        int row = (b << RB_SHIFT) + t;
        if (row < N_NODES) {
            int b0 = cur[t << 3];
            row_ptr[row] = base + b0;
            seg[row] = make_ushort4((unsigned short)(cur[(t << 3) | 1] - b0),
                                    (unsigned short)(cur[(t << 3) | 2] - b0),
                                    (unsigned short)(cur[(t << 3) | 3] - b0),
                                    (unsigned short)(cur[(t << 3) | 4] - b0));
        }
    }
    __syncthreads();
    // pass 2: counting-sort into LDS (key order), then sequential copy-out
    for (int i = t; i < cnt; i += 1024) {
        int2 e = staging[sbase + i];
        int key = ((unsigned)e.x) >> 15;
        int pos = atomicAdd(&cur[key], 1);
        sorted[pos] = make_int2(e.x & ((1 << 18) - 1), e.y);
    }
    __syncthreads();
    for (int i = t; i < cnt; i += 1024)
        edges[base + i] = sorted[i];
}

// concat(user,item) fp32 -> packed bf16 (2 per uint), fused with concat
__global__ void convert_kernel(const float4* __restrict__ u, const float4* __restrict__ it,
                               uint2* __restrict__ xh) {
    const int NU4 = USER_NUM * EMB / 4;
    const int NT4 = N_NODES * EMB / 4;
    int i = blockIdx.x * blockDim.x + threadIdx.x;
    int stride = gridDim.x * blockDim.x;
    for (; i < NT4; i += stride) {
        float4 f = (i < NU4) ? u[i] : it[i - NU4];
        xh[i] = make_uint2(pack2(f.x, f.y), pack2(f.z, f.w));
    }
}

// Timeout-guarded grid barrier: locality-only (no data deps cross it), so a
// timeout can NEVER produce wrong results or a hang -- worst case we lose L2
// phase alignment. 16 cache-line-spread counters to avoid same-line atomic
// serialization of 1500 arrivals; sum-poll with s_memrealtime failsafe.
__device__ inline void grid_barrier(int* __restrict__ bar, int tgt) {
    __syncthreads();
    if (threadIdx.x == 0) {
        atomicAdd(&bar[(blockIdx.x & 15) << 4], 1);    // device-scope
        ull t0 = __builtin_amdgcn_s_memrealtime();
        for (;;) {
            int ssum = 0;
#pragma unroll
            for (int k = 0; k < 16; ++k)
                ssum += __hip_atomic_load(&bar[k << 4], __ATOMIC_RELAXED,
                                          __HIP_MEMORY_SCOPE_AGENT);
            if (ssum >= tgt) break;
            if (__builtin_amdgcn_s_memrealtime() - t0 > 20000ull) break; // ~200us
            __builtin_amdgcn_s_sleep(16);
        }
    }
    __syncthreads();
}

// ---------------- phased SpMM + perturbation + mean ----------------
// 1500 blocks (6/CU, all co-resident: 25.6KB LDS * 6 = 154KB, launch_bounds
// (256,6)), 4 waves/block, RPW=25 rows/wave, 150000 rows exactly. Edges are
// (row, chunk)-sorted; phase c touches only x-rows of chunk c (4MB = one XCD
// L2). Grid barrier between phases enforces device-wide alignment (round-4
// showed drift destroys locality without it). Inner loop is 8-slot (1 edge
// per 8-lane group) since mean segment = 32/5 = 6.4 edges (16-slot wasted
// 2.5x issue slots in round 4).
// mode 0: out = v ; mode 1: out += v ; mode 2: out = (out+v)/3
__global__ __launch_bounds__(256, 6) void spmm_layer_kernel(
        const uint* __restrict__ x, uint* __restrict__ x_out,
        const int* __restrict__ row_ptr, const ushort4* __restrict__ seg,
        const int2* __restrict__ edges, const float* __restrict__ noise_k,
        float* __restrict__ out, int* __restrict__ bar, int mode) {
    __shared__ float accs[4][RPW * 64];                 // 25.6 KB
    int lane = threadIdx.x & 63;
    int wv = threadIdx.x >> 6;
    int r0 = (blockIdx.x * 4 + wv) * RPW;
    int g = lane >> 3;        // edge group 0..7
    int sub = lane & 7;       // dim slice: dims [sub*8, sub*8+8)

    float* ac = accs[wv];
    for (int k = lane; k < RPW * 64; k += 64) ac[k] = 0.f;

    grid_barrier(bar, SPMM_BLOCKS);                     // align phase 0 start

#pragma unroll
    for (int c = 0; c < NCHUNK; ++c) {
        for (int j = 0; j < RPW; ++j) {
            int r = r0 + j;
            int beg = row_ptr[r];
            int deg = row_ptr[r + 1] - beg;
            ushort4 s4 = seg[r];
            int blo = (c == 0) ? 0 : (c == 1) ? s4.x : (c == 2) ? s4.y
                     : (c == 3) ? s4.z : s4.w;
            int bhi = (c == 0) ? s4.x : (c == 1) ? s4.y : (c == 2) ? s4.z
                     : (c == 3) ? s4.w : deg;
            if (blo >= bhi) continue;
            int lo = beg + blo, hi = beg + bhi, lim = hi - 1;

            float a0 = 0.f, a1 = 0.f, a2 = 0.f, a3 = 0.f;
            float a4 = 0.f, a5 = 0.f, a6 = 0.f, a7 = 0.f;
            for (int bb = lo; bb < hi; bb += 8) {
                int i0 = bb + g;
                int2 e0 = edges[min(i0, lim)];
                const uint4* q0 = (const uint4*)(x + (ull)(uint)e0.x * (EMB / 2));
                uint4 h0 = q0[sub];
                float w0 = (i0 < hi) ? __int_as_float(e0.y) : 0.f;
                a0 += w0 * bflo(h0.x); a1 += w0 * bfhi(h0.x);
                a2 += w0 * bflo(h0.y); a3 += w0 * bfhi(h0.y);
                a4 += w0 * bflo(h0.z); a5 += w0 * bfhi(h0.z);
                a6 += w0 * bflo(h0.w); a7 += w0 * bfhi(h0.w);
            }
            // fold the 8 edge-groups
#pragma unroll
            for (int off = 8; off <= 32; off <<= 1) {
                a0 += __shfl_xor(a0, off, 64); a1 += __shfl_xor(a1, off, 64);
                a2 += __shfl_xor(a2, off, 64); a3 += __shfl_xor(a3, off, 64);
                a4 += __shfl_xor(a4, off, 64); a5 += __shfl_xor(a5, off, 64);
                a6 += __shfl_xor(a6, off, 64); a7 += __shfl_xor(a7, off, 64);
            }
            if (g == 0) {                        // 8 lanes, disjoint dims
                float* ap = ac + j * 64 + sub * 8;
                ap[0] += a0; ap[1] += a1; ap[2] += a2; ap[3] += a3;
                ap[4] += a4; ap[5] += a5; ap[6] += a6; ap[7] += a7;
            }
        }
        if (c < NCHUNK - 1)
            grid_barrier(bar + (c + 1) * BAR_STRIDE, SPMM_BLOCKS);
    }

    // finalize: perturbation + output (lane d owns dim d)
    for (int j = 0; j < RPW; ++j) {
        int r = r0 + j;
        float a = ac[j * 64 + lane];
        float nv = noise_k[(ull)r * EMB + lane];
        float ss = nv * nv;
        ss += __shfl_xor(ss, 1, 64);
        ss += __shfl_xor(ss, 2, 64);
        ss += __shfl_xor(ss, 4, 64);
        ss += __shfl_xor(ss, 8, 64);
        ss += __shfl_xor(ss, 16, 64);
        ss += __shfl_xor(ss, 32, 64);
        float s = EPS_F / fmaxf(sqrtf(ss), NORM_EPS_F);
        float sg = (a > 0.f) ? 1.f : ((a < 0.f) ? -1.f : 0.f);
        float v = a + sg * nv * s;
        ull o = (ull)r * EMB + lane;
        if (mode == 0) out[o] = v;
        else if (mode == 1) out[o] += v;
        else out[o] = (out[o] + v) * (1.f / 3.f);
        if (mode != 2) {
            float v2 = __shfl_xor(v, 1, 64);
            if (!(lane & 1))
                x_out[(ull)r * (EMB / 2) + (lane >> 1)] = pack2(v, v2);
        }
    }
}

// ---------------- launch ----------------

extern "C" void kernel_launch(void* const* d_in, const int* in_sizes, int n_in,
                              void* d_out, int out_size, void* d_ws, size_t ws_size,
                              hipStream_t stream) {
    const float* user_emb = (const float*)d_in[0];
    const float* item_emb = (const float*)d_in[1];
    const int*   adj_rows = (const int*)d_in[2];
    const int*   adj_cols = (const int*)d_in[3];
    const float* adj_vals = (const float*)d_in[4];
    const float* noise    = (const float*)d_in[5];
    float* out = (float*)d_out;

    char* ws = (char*)d_ws;
    size_t off = 0;
    auto alloc = [&](size_t bytes) {
        char* p = ws + off;
        off += (bytes + 15) & ~size_t(15);
        return p;
    };
    int*     row_ptr     = (int*)alloc((N_NODES + 1) * sizeof(int));
    int*     gcursor     = (int*)alloc(NB * sizeof(int));
    int*     bucket_base = (int*)alloc(NB * sizeof(int));
    int*     bar         = (int*)alloc(NBAR * BAR_STRIDE * sizeof(int));
    ushort4* seg         = (ushort4*)alloc((size_t)N_NODES * sizeof(ushort4));
    int2*    edges       = (int2*)alloc((size_t)NNZ * sizeof(int2));
    int2*    staging     = (int2*)alloc((size_t)NB * CAP * sizeof(int2));  // 43.2 MB
    // bf16 x buffers alias staging (staging dead after binB; xh_a written by
    // convert_kernel which runs after binB; xh_b first written by layer 0).
    uint* xh_a = (uint*)staging;                                   // 19.2 MB
    uint* xh_b = (uint*)((char*)staging + (size_t)N_NODES * EMB * 2);

    // ---- CSR build ----
    init_all<<<16, 256, 0, stream>>>(gcursor, bar);
    binA_kernel<<<BINA_GRID, 1024, 0, stream>>>(adj_rows, adj_cols, adj_vals,
                                                gcursor, staging);
    bscan_kernel<<<1, 1024, 0, stream>>>(gcursor, bucket_base, row_ptr);
    binB_kernel<<<NB, 1024, 0, stream>>>(gcursor, bucket_base, staging, edges,
                                         row_ptr, seg);

    // ---- fp32 -> bf16 convert (fused concat) ----
    convert_kernel<<<2048, 256, 0, stream>>>((const float4*)user_emb,
                                             (const float4*)item_emb, (uint2*)xh_a);

    // ---- 3 layers ----
    const size_t NE = (size_t)N_NODES * EMB;
    spmm_layer_kernel<<<SPMM_BLOCKS, 256, 0, stream>>>(
        xh_a, xh_b, row_ptr, seg, edges, noise + 0 * NE, out,
        bar + 0 * 5 * BAR_STRIDE, 0);
    spmm_layer_kernel<<<SPMM_BLOCKS, 256, 0, stream>>>(
        xh_b, xh_a, row_ptr, seg, edges, noise + 1 * NE, out,
        bar + 1 * 5 * BAR_STRIDE, 1);
    spmm_layer_kernel<<<SPMM_BLOCKS, 256, 0, stream>>>(
        xh_a, nullptr, row_ptr, seg, edges, noise + 2 * NE, out,
        bar + 2 * 5 * BAR_STRIDE, 2);
}

// Round 6
// 1556.805 us; speedup vs baseline: 1.1933x; 1.1933x over previous
//
#include <hip/hip_runtime.h>

typedef unsigned int uint;
typedef unsigned long long ull;

#define USER_NUM   100000
#define ITEM_NUM   50000
#define N_NODES    (USER_NUM + ITEM_NUM)
#define NNZ        4800000
#define EMB        64
#define EPS_F      0.2f
#define NORM_EPS_F 1e-12f

// buckets of 256 rows
#define RB_SHIFT   8
#define RB         256
#define NB         ((N_NODES + RB - 1) / RB)     // 586
#define CAP        9216                           // mean 8191, std ~90 -> +11 sigma
#define BINA_CHUNK 8192
#define BINA_GRID  ((NNZ + BINA_CHUNK - 1) / BINA_CHUNK)  // 586

// column chunking for spmm L2 locality: 32768 rows * 128 B = 4 MB = one XCD L2
#define CSHIFT     15
#define NCHUNK     5                              // ceil(150000 / 32768)
#define NKEY       2048                           // 256 rows * 8 chunk slots
#define RPW        37                             // rows per wave
#define SPMM_BLOCKS 1024                          // 4/CU exactly -> co-resident
#define BAR_STRIDE 256                            // ints per barrier (16 ctr * 16 ints)
#define NBAR       15                             // 5 per layer * 3 layers

// ---------------- bf16 helpers ----------------
__device__ inline float bflo(uint u) { return __uint_as_float(u << 16); }
__device__ inline float bfhi(uint u) { return __uint_as_float(u & 0xffff0000u); }
__device__ inline uint f2bf(float f) {                 // RNE round to bf16
    uint u = __float_as_uint(f);
    return (u + 0x7fffu + ((u >> 16) & 1u)) >> 16;
}
__device__ inline uint pack2(float a, float b) { return f2bf(a) | (f2bf(b) << 16); }

// ---------------- CSR build ----------------

__global__ void init_all(int* __restrict__ g, int* __restrict__ bar) {
    int i = blockIdx.x * blockDim.x + threadIdx.x;
    if (i < NB) g[i] = i * CAP;
    if (i < NBAR * BAR_STRIDE) bar[i] = 0;
}

// Phase A: block-level LDS counting sort by bucket; bid array for copy-out.
// Sequential copy-out -> coalesced full-line global writes.
__global__ __launch_bounds__(1024) void binA_kernel(const int* __restrict__ rows,
                                                    const int* __restrict__ cols,
                                                    const float* __restrict__ vals,
                                                    int* __restrict__ gcursor,
                                                    int2* __restrict__ staging) {
    __shared__ int2 data[BINA_CHUNK];            // 64 KB
    __shared__ unsigned short bid[BINA_CHUNK];   // 16 KB
    __shared__ int hist[NB];
    __shared__ int rstart[NB + 1];
    __shared__ int gbase[NB];
    __shared__ int lcur[NB];
    __shared__ int wsum[16];
    int t = threadIdx.x;
    int cbeg = blockIdx.x * BINA_CHUNK;
    int cend = min(cbeg + BINA_CHUNK, NNZ);
    int total = cend - cbeg;

    int r[8];
    if (t < NB) hist[t] = 0;
    __syncthreads();
#pragma unroll
    for (int k = 0; k < 8; ++k) {
        int i = cbeg + (k << 10) + t;
        r[k] = (i < cend) ? rows[i] : -1;
        if (r[k] >= 0) atomicAdd(&hist[r[k] >> RB_SHIFT], 1);
    }
    __syncthreads();

    // 2-barrier hierarchical shfl scan of hist -> exclusive run starts
    int v = (t < NB) ? hist[t] : 0;
    int sc = v;
#pragma unroll
    for (int off = 1; off < 64; off <<= 1) {
        int u = __shfl_up(sc, off, 64);
        if ((t & 63) >= off) sc += u;
    }
    if ((t & 63) == 63) wsum[t >> 6] = sc;
    __syncthreads();
    if (t < 64) {
        int ws = (t < 16) ? wsum[t] : 0;
#pragma unroll
        for (int off = 1; off < 16; off <<= 1) {
            int u = __shfl_up(ws, off, 64);
            if (t >= off) ws += u;
        }
        if (t < 16) wsum[t] = ws;
    }
    __syncthreads();
    int wid = t >> 6;
    int excl = sc - v + ((wid > 0) ? wsum[wid - 1] : 0);
    if (t <= NB) rstart[t] = excl;            // rstart[NB] == total
    if (t < NB) {
        gbase[t] = atomicAdd(&gcursor[t], hist[t]);   // one global atomic per bucket
        lcur[t] = 0;
    }
    __syncthreads();

    // sort into LDS by bucket, recording bucket id per slot
#pragma unroll
    for (int k = 0; k < 8; ++k) {
        if (r[k] >= 0) {
            int i = cbeg + (k << 10) + t;
            int b = r[k] >> RB_SHIFT;
            int pos = rstart[b] + atomicAdd(&lcur[b], 1);
            data[pos] = make_int2(((r[k] & (RB - 1)) << 18) | cols[i],
                                  __float_as_int(vals[i]));
            bid[pos] = (unsigned short)b;
        }
    }
    __syncthreads();

    // sequential copy-out: consecutive threads -> consecutive global addresses
    for (int i = t; i < total; i += 1024) {
        int b = bid[i];
        staging[(long)gbase[b] + (i - rstart[b])] = data[i];
    }
}

// exclusive scan of bucket counts -> bucket_base; sentinel row_ptr[N_NODES]
__global__ __launch_bounds__(1024) void bscan_kernel(const int* __restrict__ gcursor,
                                                     int* __restrict__ bucket_base,
                                                     int* __restrict__ row_ptr) {
    __shared__ int wsum[16];
    int t = threadIdx.x;
    int c = (t < NB) ? (gcursor[t] - t * CAP) : 0;
    int sc = c;
#pragma unroll
    for (int off = 1; off < 64; off <<= 1) {
        int u = __shfl_up(sc, off, 64);
        if ((t & 63) >= off) sc += u;
    }
    if ((t & 63) == 63) wsum[t >> 6] = sc;
    __syncthreads();
    if (t < 64) {
        int ws = (t < 16) ? wsum[t] : 0;
#pragma unroll
        for (int off = 1; off < 16; off <<= 1) {
            int u = __shfl_up(ws, off, 64);
            if (t >= off) ws += u;
        }
        if (t < 16) wsum[t] = ws;
    }
    __syncthreads();
    int wid = t >> 6;
    int excl = sc - c + ((wid > 0) ? wsum[wid - 1] : 0);
    if (t < NB) bucket_base[t] = excl;
    if (t == 0) row_ptr[N_NODES] = NNZ;
}

// Phase B: one 1024-thread block per 256-row bucket. Counting sort by key
// (row_local<<3)|col_chunk == (e.x >> 15). Persists per-row chunk boundaries
// (seg[row], relative to row start). Sequential copy-out -> line-dense writes.
__global__ __launch_bounds__(1024) void binB_kernel(const int* __restrict__ gcursor,
                                                    const int* __restrict__ bucket_base,
                                                    const int2* __restrict__ staging,
                                                    int2* __restrict__ edges,
                                                    int* __restrict__ row_ptr,
                                                    ushort4* __restrict__ seg) {
    __shared__ int2 sorted[CAP];      // 72 KB
    __shared__ int s[NKEY];           // 8 KB
    __shared__ int cur[NKEY];         // 8 KB
    __shared__ int wsum[16];
    int b = blockIdx.x;
    int t = threadIdx.x;
    int cnt = gcursor[b] - b * CAP;
    long sbase = (long)b * CAP;
    int base = bucket_base[b];

    s[t] = 0;
    s[t + 1024] = 0;
    __syncthreads();
    // pass 1: histogram by (row_local, chunk) key
    for (int i = t; i < cnt; i += 1024)
        atomicAdd(&s[((unsigned)staging[sbase + i].x) >> 15], 1);
    __syncthreads();

    // scan 2048 keys: pair-per-thread + hierarchical shfl scan
    int v0 = s[2 * t], v1 = s[2 * t + 1];
    int pv = v0 + v1;
    int sc = pv;
#pragma unroll
    for (int off = 1; off < 64; off <<= 1) {
        int u = __shfl_up(sc, off, 64);
        if ((t & 63) >= off) sc += u;
    }
    if ((t & 63) == 63) wsum[t >> 6] = sc;
    __syncthreads();
    if (t < 64) {
        int ws = (t < 16) ? wsum[t] : 0;
#pragma unroll
        for (int off = 1; off < 16; off <<= 1) {
            int u = __shfl_up(ws, off, 64);
            if (t >= off) ws += u;
        }
        if (t < 16) wsum[t] = ws;
    }
    __syncthreads();
    int wid = t >> 6;
    int ex = sc - pv + ((wid > 0) ? wsum[wid - 1] : 0);
    cur[2 * t] = ex;
    cur[2 * t + 1] = ex + v0;
    __syncthreads();

    if (t < RB) {
        int row = (b << RB_SHIFT) + t;
        if (row < N_NODES) {
            int b0 = cur[t << 3];
            row_ptr[row] = base + b0;
            seg[row] = make_ushort4((unsigned short)(cur[(t << 3) | 1] - b0),
                                    (unsigned short)(cur[(t << 3) | 2] - b0),
                                    (unsigned short)(cur[(t << 3) | 3] - b0),
                                    (unsigned short)(cur[(t << 3) | 4] - b0));
        }
    }
    __syncthreads();
    // pass 2: counting-sort into LDS (key order), then sequential copy-out
    for (int i = t; i < cnt; i += 1024) {
        int2 e = staging[sbase + i];
        int key = ((unsigned)e.x) >> 15;
        int pos = atomicAdd(&cur[key], 1);
        sorted[pos] = make_int2(e.x & ((1 << 18) - 1), e.y);
    }
    __syncthreads();
    for (int i = t; i < cnt; i += 1024)
        edges[base + i] = sorted[i];
}

// concat(user,item) fp32 -> packed bf16 (2 per uint), fused with concat
__global__ void convert_kernel(const float4* __restrict__ u, const float4* __restrict__ it,
                               uint2* __restrict__ xh) {
    const int NU4 = USER_NUM * EMB / 4;
    const int NT4 = N_NODES * EMB / 4;
    int i = blockIdx.x * blockDim.x + threadIdx.x;
    int stride = gridDim.x * blockDim.x;
    for (; i < NT4; i += stride) {
        float4 f = (i < NU4) ? u[i] : it[i - NU4];
        xh[i] = make_uint2(pack2(f.x, f.y), pack2(f.z, f.w));
    }
}

// Timeout-guarded grid barrier: locality-only (no data deps cross it) -- a
// timeout can never produce wrong results or a hang, only lost L2 alignment.
// 16 cache-line-spread counters; ~50us failsafe.
__device__ inline void grid_barrier(int* __restrict__ bar, int tgt) {
    __syncthreads();
    if (threadIdx.x == 0) {
        atomicAdd(&bar[(blockIdx.x & 15) << 4], 1);
        ull t0 = __builtin_amdgcn_s_memrealtime();
        for (;;) {
            int ssum = 0;
#pragma unroll
            for (int k = 0; k < 16; ++k)
                ssum += __hip_atomic_load(&bar[k << 4], __ATOMIC_RELAXED,
                                          __HIP_MEMORY_SCOPE_AGENT);
            if (ssum >= tgt) break;
            if (__builtin_amdgcn_s_memrealtime() - t0 > 5000ull) break; // ~50us
            __builtin_amdgcn_s_sleep(8);
        }
    }
    __syncthreads();
}

// ---------------- phased SpMM + perturbation + mean ----------------
// DIM-PARALLEL waves (round-5 postmortem: edge-parallel + per-segment shfl
// fold saturated the DS pipe, VALUBusy 19%). Lane l owns dim-pair 2(l&31);
// lanes 0-31 process edge i, lanes 32-63 edge i+1; per edge the half-wave
// reads the full 128B x row coalesced. 8 edges/iter = 4 independent gather
// chains. Per (row,chunk) segment the DS-pipe cost is 2 shfl + 1 float2 LDS
// rmw (was ~40 wave-instrs). 1024 blocks = 4/CU exactly (LDS 37.9KB) ->
// co-resident by construction; grid barrier aligns chunk phases (proven:
// FETCH 550->260MB in round 5).
// mode 0: out = v ; mode 1: out += v ; mode 2: out = (out+v)/3
__global__ __launch_bounds__(256, 4) void spmm_layer_kernel(
        const uint* __restrict__ x, uint* __restrict__ x_out,
        const int* __restrict__ row_ptr, const ushort4* __restrict__ seg,
        const int2* __restrict__ edges, const float* __restrict__ noise_k,
        float* __restrict__ out, int* __restrict__ bar, int mode) {
    __shared__ float accs[4][RPW * 64];                 // 37888 B
    int lane = threadIdx.x & 63;
    int wv = threadIdx.x >> 6;
    int r0 = (blockIdx.x * 4 + wv) * RPW;
    int half = lane >> 5;     // which edge of the pair
    int m = lane & 31;        // uint index in row = dim pair (2m, 2m+1)

    float* ac = accs[wv];
    for (int k = lane; k < RPW * 64; k += 64) ac[k] = 0.f;
    int nr = (r0 < N_NODES) ? min(RPW, N_NODES - r0) : 0;

    grid_barrier(bar, SPMM_BLOCKS);                     // align phase 0 start

    for (int c = 0; c < NCHUNK; ++c) {
        for (int j = 0; j < nr; ++j) {
            int r = r0 + j;
            int beg = row_ptr[r];
            int deg = row_ptr[r + 1] - beg;
            ushort4 s4 = seg[r];
            int blo = (c == 0) ? 0 : (c == 1) ? s4.x : (c == 2) ? s4.y
                     : (c == 3) ? s4.z : s4.w;
            int bhi = (c == 0) ? s4.x : (c == 1) ? s4.y : (c == 2) ? s4.z
                     : (c == 3) ? s4.w : deg;
            if (blo >= bhi) continue;
            int lo = beg + blo, hi = beg + bhi, lim = hi - 1;

            float a0 = 0.f, a1 = 0.f;
            for (int bb = lo; bb < hi; bb += 8) {
                int i0 = bb + half, i1 = bb + 2 + half;
                int i2 = bb + 4 + half, i3 = bb + 6 + half;
                int2 e0 = edges[min(i0, lim)];
                int2 e1 = edges[min(i1, lim)];
                int2 e2 = edges[min(i2, lim)];
                int2 e3 = edges[min(i3, lim)];
                uint u0 = x[(ull)(uint)e0.x * (EMB / 2) + m];
                uint u1 = x[(ull)(uint)e1.x * (EMB / 2) + m];
                uint u2 = x[(ull)(uint)e2.x * (EMB / 2) + m];
                uint u3 = x[(ull)(uint)e3.x * (EMB / 2) + m];
                float w0 = (i0 < hi) ? __int_as_float(e0.y) : 0.f;
                float w1 = (i1 < hi) ? __int_as_float(e1.y) : 0.f;
                float w2 = (i2 < hi) ? __int_as_float(e2.y) : 0.f;
                float w3 = (i3 < hi) ? __int_as_float(e3.y) : 0.f;
                a0 += w0 * bflo(u0); a1 += w0 * bfhi(u0);
                a0 += w1 * bflo(u1); a1 += w1 * bfhi(u1);
                a0 += w2 * bflo(u2); a1 += w2 * bfhi(u2);
                a0 += w3 * bflo(u3); a1 += w3 * bfhi(u3);
            }
            // combine the two half-wave edge slots (dims are lane-local)
            a0 += __shfl_xor(a0, 32, 64);
            a1 += __shfl_xor(a1, 32, 64);
            if (half == 0) {
                float* ap = ac + j * 64 + 2 * m;
                ap[0] += a0;
                ap[1] += a1;
            }
        }
        if (c < NCHUNK - 1)
            grid_barrier(bar + (c + 1) * BAR_STRIDE, SPMM_BLOCKS);
    }

    // finalize: perturbation + output (lane d owns dim d)
    for (int j = 0; j < nr; ++j) {
        int r = r0 + j;
        float a = ac[j * 64 + lane];
        float nv = noise_k[(ull)r * EMB + lane];
        float ss = nv * nv;
        ss += __shfl_xor(ss, 1, 64);
        ss += __shfl_xor(ss, 2, 64);
        ss += __shfl_xor(ss, 4, 64);
        ss += __shfl_xor(ss, 8, 64);
        ss += __shfl_xor(ss, 16, 64);
        ss += __shfl_xor(ss, 32, 64);
        float s = EPS_F / fmaxf(sqrtf(ss), NORM_EPS_F);
        float sg = (a > 0.f) ? 1.f : ((a < 0.f) ? -1.f : 0.f);
        float v = a + sg * nv * s;
        ull o = (ull)r * EMB + lane;
        if (mode == 0) out[o] = v;
        else if (mode == 1) out[o] += v;
        else out[o] = (out[o] + v) * (1.f / 3.f);
        if (mode != 2) {
            float v2 = __shfl_xor(v, 1, 64);
            if (!(lane & 1))
                x_out[(ull)r * (EMB / 2) + (lane >> 1)] = pack2(v, v2);
        }
    }
}

// ---------------- launch ----------------

extern "C" void kernel_launch(void* const* d_in, const int* in_sizes, int n_in,
                              void* d_out, int out_size, void* d_ws, size_t ws_size,
                              hipStream_t stream) {
    const float* user_emb = (const float*)d_in[0];
    const float* item_emb = (const float*)d_in[1];
    const int*   adj_rows = (const int*)d_in[2];
    const int*   adj_cols = (const int*)d_in[3];
    const float* adj_vals = (const float*)d_in[4];
    const float* noise    = (const float*)d_in[5];
    float* out = (float*)d_out;

    char* ws = (char*)d_ws;
    size_t off = 0;
    auto alloc = [&](size_t bytes) {
        char* p = ws + off;
        off += (bytes + 15) & ~size_t(15);
        return p;
    };
    int*     row_ptr     = (int*)alloc((N_NODES + 1) * sizeof(int));
    int*     gcursor     = (int*)alloc(NB * sizeof(int));
    int*     bucket_base = (int*)alloc(NB * sizeof(int));
    int*     bar         = (int*)alloc(NBAR * BAR_STRIDE * sizeof(int));
    ushort4* seg         = (ushort4*)alloc((size_t)N_NODES * sizeof(ushort4));
    int2*    edges       = (int2*)alloc((size_t)NNZ * sizeof(int2));
    int2*    staging     = (int2*)alloc((size_t)NB * CAP * sizeof(int2));  // 43.2 MB
    // bf16 x buffers alias staging (staging dead after binB; xh_a written by
    // convert_kernel which runs after binB; xh_b first written by layer 0).
    uint* xh_a = (uint*)staging;                                   // 19.2 MB
    uint* xh_b = (uint*)((char*)staging + (size_t)N_NODES * EMB * 2);

    // ---- CSR build ----
    init_all<<<16, 256, 0, stream>>>(gcursor, bar);
    binA_kernel<<<BINA_GRID, 1024, 0, stream>>>(adj_rows, adj_cols, adj_vals,
                                                gcursor, staging);
    bscan_kernel<<<1, 1024, 0, stream>>>(gcursor, bucket_base, row_ptr);
    binB_kernel<<<NB, 1024, 0, stream>>>(gcursor, bucket_base, staging, edges,
                                         row_ptr, seg);

    // ---- fp32 -> bf16 convert (fused concat) ----
    convert_kernel<<<2048, 256, 0, stream>>>((const float4*)user_emb,
                                             (const float4*)item_emb, (uint2*)xh_a);

    // ---- 3 layers ----
    const size_t NE = (size_t)N_NODES * EMB;
    spmm_layer_kernel<<<SPMM_BLOCKS, 256, 0, stream>>>(
        xh_a, xh_b, row_ptr, seg, edges, noise + 0 * NE, out,
        bar + 0 * 5 * BAR_STRIDE, 0);
    spmm_layer_kernel<<<SPMM_BLOCKS, 256, 0, stream>>>(
        xh_b, xh_a, row_ptr, seg, edges, noise + 1 * NE, out,
        bar + 1 * 5 * BAR_STRIDE, 1);
    spmm_layer_kernel<<<SPMM_BLOCKS, 256, 0, stream>>>(
        xh_a, nullptr, row_ptr, seg, edges, noise + 2 * NE, out,
        bar + 2 * 5 * BAR_STRIDE, 2);
}

// Round 7
// 750.197 us; speedup vs baseline: 2.4764x; 2.0752x over previous
//
#include <hip/hip_runtime.h>

typedef unsigned int uint;

#define USER_NUM   100000
#define ITEM_NUM   50000
#define N_NODES    (USER_NUM + ITEM_NUM)
#define NNZ        4800000
#define EMB        64
#define EPS_F      0.2f
#define NORM_EPS_F 1e-12f

// buckets of 256 rows
#define RB_SHIFT   8
#define RB         256
#define NB         ((N_NODES + RB - 1) / RB)     // 586
#define CAP        9216                           // mean 8191, std ~90 -> +11 sigma
#define BINA_CHUNK 4096
#define BINA_GRID  ((NNZ + BINA_CHUNK - 1) / BINA_CHUNK)  // 1172
#define BB_K       9                              // ceil(CAP / 1024)

// ---------------- bf16 helpers ----------------
__device__ inline float bflo(uint u) { return __uint_as_float(u << 16); }
__device__ inline float bfhi(uint u) { return __uint_as_float(u & 0xffff0000u); }
__device__ inline uint f2bf(float f) {                 // RNE round to bf16
    uint u = __float_as_uint(f);
    return (u + 0x7fffu + ((u >> 16) & 1u)) >> 16;
}
__device__ inline uint pack2(float a, float b) { return f2bf(a) | (f2bf(b) << 16); }

// ---------------- CSR build ----------------

__global__ void init_gcursor(int* __restrict__ g) {
    int b = blockIdx.x * blockDim.x + threadIdx.x;
    if (b < NB) g[b] = b * CAP;
}

// Phase A: block-level LDS counting sort by bucket. Chunk 4096 / 512 threads:
// LDS 49.2KB -> 3 blocks/CU (round-3 90KB variant ran 1 block/CU with nothing
// to overlap its barrier phases). rows/cols/vals cached in registers -> each
// input byte read exactly once. Sequential copy-out -> coalesced writes.
__global__ __launch_bounds__(512) void binA_kernel(const int* __restrict__ rows,
                                                   const int* __restrict__ cols,
                                                   const float* __restrict__ vals,
                                                   int* __restrict__ gcursor,
                                                   int2* __restrict__ staging) {
    __shared__ int2 data[BINA_CHUNK];            // 32 KB
    __shared__ unsigned short bid[BINA_CHUNK];   // 8 KB
    __shared__ int hist[NB];
    __shared__ int rstart[NB + 1];
    __shared__ int gbase[NB];
    __shared__ int lcur[NB];
    __shared__ int wsum[8];
    int t = threadIdx.x;
    int cbeg = blockIdx.x * BINA_CHUNK;
    int cend = min(cbeg + BINA_CHUNK, NNZ);
    int total = cend - cbeg;

    int r[8], c[8];
    float v[8];
    if (t < NB) hist[t] = 0;
    if (t + 512 < NB) hist[t + 512] = 0;
    __syncthreads();
#pragma unroll
    for (int k = 0; k < 8; ++k) {
        int i = cbeg + (k << 9) + t;
        bool ok = i < cend;
        r[k] = ok ? rows[i] : -1;
        c[k] = ok ? cols[i] : 0;
        v[k] = ok ? vals[i] : 0.f;
    }
#pragma unroll
    for (int k = 0; k < 8; ++k)
        if (r[k] >= 0) atomicAdd(&hist[r[k] >> RB_SHIFT], 1);
    __syncthreads();

    // pair-per-thread hierarchical shfl scan over 1024 slots (NB=586)
    int v0 = (2 * t < NB) ? hist[2 * t] : 0;
    int v1 = (2 * t + 1 < NB) ? hist[2 * t + 1] : 0;
    int pv = v0 + v1;
    int sc = pv;
#pragma unroll
    for (int off = 1; off < 64; off <<= 1) {
        int u = __shfl_up(sc, off, 64);
        if ((t & 63) >= off) sc += u;
    }
    if ((t & 63) == 63) wsum[t >> 6] = sc;
    __syncthreads();
    if (t < 64) {
        int ws = (t < 8) ? wsum[t] : 0;
#pragma unroll
        for (int off = 1; off < 8; off <<= 1) {
            int u = __shfl_up(ws, off, 64);
            if (t >= off) ws += u;
        }
        if (t < 8) wsum[t] = ws;
    }
    __syncthreads();
    int wid = t >> 6;
    int ex = sc - pv + ((wid > 0) ? wsum[wid - 1] : 0);
    if (2 * t <= NB) rstart[2 * t] = ex;
    if (2 * t + 1 <= NB) rstart[2 * t + 1] = ex + v0;
    if (2 * t < NB) { gbase[2 * t] = atomicAdd(&gcursor[2 * t], v0); lcur[2 * t] = 0; }
    if (2 * t + 1 < NB) { gbase[2 * t + 1] = atomicAdd(&gcursor[2 * t + 1], v1); lcur[2 * t + 1] = 0; }
    __syncthreads();

    // sort into LDS by bucket, recording bucket id per slot
#pragma unroll
    for (int k = 0; k < 8; ++k) {
        if (r[k] >= 0) {
            int b = r[k] >> RB_SHIFT;
            int pos = rstart[b] + atomicAdd(&lcur[b], 1);
            data[pos] = make_int2(((r[k] & (RB - 1)) << 18) | c[k],
                                  __float_as_int(v[k]));
            bid[pos] = (unsigned short)b;
        }
    }
    __syncthreads();

    // sequential copy-out: consecutive threads -> consecutive global addresses
    for (int i = t; i < total; i += 512) {
        int b = bid[i];
        staging[(long)gbase[b] + (i - rstart[b])] = data[i];
    }
}

// exclusive scan of bucket counts -> bucket_base; sentinel row_ptr[N_NODES]
__global__ __launch_bounds__(1024) void bscan_kernel(const int* __restrict__ gcursor,
                                                     int* __restrict__ bucket_base,
                                                     int* __restrict__ row_ptr) {
    __shared__ int wsum[16];
    int t = threadIdx.x;
    int c = (t < NB) ? (gcursor[t] - t * CAP) : 0;
    int sc = c;
#pragma unroll
    for (int off = 1; off < 64; off <<= 1) {
        int u = __shfl_up(sc, off, 64);
        if ((t & 63) >= off) sc += u;
    }
    if ((t & 63) == 63) wsum[t >> 6] = sc;
    __syncthreads();
    if (t < 64) {
        int ws = (t < 16) ? wsum[t] : 0;
#pragma unroll
        for (int off = 1; off < 16; off <<= 1) {
            int u = __shfl_up(ws, off, 64);
            if (t >= off) ws += u;
        }
        if (t < 16) wsum[t] = ws;
    }
    __syncthreads();
    int wid = t >> 6;
    int excl = sc - c + ((wid > 0) ? wsum[wid - 1] : 0);
    if (t < NB) bucket_base[t] = excl;
    if (t == 0) row_ptr[N_NODES] = NNZ;
}

// Phase B: one 1024-thread block per 256-row bucket. Staging read ONCE into
// registers (round-3 version read it twice: hist pass + sort pass); LDS
// counting sort; sequential copy-out -> line-dense writes. 74KB LDS -> 2
// blocks/CU = 32 waves/CU.
__global__ __launch_bounds__(1024) void binB_kernel(const int* __restrict__ gcursor,
                                                    const int* __restrict__ bucket_base,
                                                    const int2* __restrict__ staging,
                                                    int2* __restrict__ edges,
                                                    int* __restrict__ row_ptr) {
    __shared__ int2 sorted[CAP];      // 72 KB
    __shared__ int s[RB];
    __shared__ int cur[RB];
    __shared__ int wsum[16];
    int b = blockIdx.x;
    int t = threadIdx.x;
    int cnt = gcursor[b] - b * CAP;
    long sbase = (long)b * CAP;
    int base = bucket_base[b];

    int2 e[BB_K];
    if (t < RB) s[t] = 0;
    __syncthreads();
#pragma unroll
    for (int k = 0; k < BB_K; ++k) {
        int i = (k << 10) + t;
        e[k] = (i < cnt) ? staging[sbase + i] : make_int2(-1, 0);
    }
#pragma unroll
    for (int k = 0; k < BB_K; ++k)
        if (e[k].x >= 0) atomicAdd(&s[((unsigned)e[k].x) >> 18], 1);
    __syncthreads();

    int v = (t < RB) ? s[t] : 0;
    int sc = v;
#pragma unroll
    for (int off = 1; off < 64; off <<= 1) {
        int u = __shfl_up(sc, off, 64);
        if ((t & 63) >= off) sc += u;
    }
    if ((t & 63) == 63) wsum[t >> 6] = sc;
    __syncthreads();
    if (t < 64) {
        int ws = (t < 16) ? wsum[t] : 0;
#pragma unroll
        for (int off = 1; off < 16; off <<= 1) {
            int u = __shfl_up(ws, off, 64);
            if (t >= off) ws += u;
        }
        if (t < 16) wsum[t] = ws;
    }
    __syncthreads();
    int wid = t >> 6;
    int excl = sc - v + ((wid > 0) ? wsum[wid - 1] : 0);

    int row = (b << RB_SHIFT) + t;
    if (t < RB) {
        if (row < N_NODES) row_ptr[row] = base + excl;
        cur[t] = excl;
    }
    __syncthreads();
    // counting-sort from registers into LDS
#pragma unroll
    for (int k = 0; k < BB_K; ++k) {
        if (e[k].x >= 0) {
            int rl = ((unsigned)e[k].x) >> 18;
            int pos = atomicAdd(&cur[rl], 1);
            sorted[pos] = make_int2(e[k].x & ((1 << 18) - 1), e[k].y);
        }
    }
    __syncthreads();
    // sequential coalesced copy-out
    for (int i = t; i < cnt; i += 1024)
        edges[base + i] = sorted[i];
}

// concat(user,item) fp32 -> packed bf16 (2 per uint), fused with concat
__global__ void convert_kernel(const float4* __restrict__ u, const float4* __restrict__ it,
                               uint2* __restrict__ xh) {
    const int NU4 = USER_NUM * EMB / 4;
    const int NT4 = N_NODES * EMB / 4;
    int i = blockIdx.x * blockDim.x + threadIdx.x;
    int stride = gridDim.x * blockDim.x;
    for (; i < NT4; i += stride) {
        float4 f = (i < NU4) ? u[i] : it[i - NU4];
        xh[i] = make_uint2(pack2(f.x, f.y), pack2(f.z, f.w));
    }
}

// ---------------- SpMM (bf16 gather) + perturbation + mean ----------------
// Round-3 known-good kernel (162us/layer). One wave per row; 8 groups of 8
// lanes; 2 edges in flight per lane (16 edges/iter/wave). Phased/L2-chunked
// variants (rounds 4-6) all lost to this despite halving HBM traffic: the L3
// already absorbs much of the gather reuse, and phasing destroyed the
// occupancy/MLP this version gets from 37500 independent blocks.
// mode 0: out = v ; mode 1: out += v ; mode 2: out = (out+v)/3
__global__ __launch_bounds__(256) void spmm_layer_kernel(const uint* __restrict__ x,
                                                         uint* __restrict__ x_out,
                                                         const int* __restrict__ row_ptr,
                                                         const int2* __restrict__ edges,
                                                         const float* __restrict__ noise_k,
                                                         float* __restrict__ out, int mode) {
    int lane = threadIdx.x & 63;
    int row = blockIdx.x * 4 + (threadIdx.x >> 6);
    if (row >= N_NODES) return;
    int g = lane >> 3;        // edge group 0..7
    int sub = lane & 7;       // dim slice: dims [sub*8, sub*8+8)

    int beg = row_ptr[row];
    int end = row_ptr[row + 1];
    int lim = end - 1;

    float a0 = 0.f, a1 = 0.f, a2 = 0.f, a3 = 0.f;
    float a4 = 0.f, a5 = 0.f, a6 = 0.f, a7 = 0.f;

    for (int base = beg; base < end; base += 16) {
        int i0 = base + g, i1 = base + 8 + g;
        int2 e0 = edges[min(i0, lim)];
        int2 e1 = edges[min(i1, lim)];
        const uint4* q0 = (const uint4*)(x + (long)e0.x * (EMB / 2));
        const uint4* q1 = (const uint4*)(x + (long)e1.x * (EMB / 2));
        uint4 h0 = q0[sub];                       // 8 bf16 dims, 16B coalesced
        uint4 h1 = q1[sub];
        float w0 = (i0 < end) ? __int_as_float(e0.y) : 0.f;
        float w1 = (i1 < end) ? __int_as_float(e1.y) : 0.f;
        a0 += w0 * bflo(h0.x); a1 += w0 * bfhi(h0.x);
        a2 += w0 * bflo(h0.y); a3 += w0 * bfhi(h0.y);
        a4 += w0 * bflo(h0.z); a5 += w0 * bfhi(h0.z);
        a6 += w0 * bflo(h0.w); a7 += w0 * bfhi(h0.w);
        a0 += w1 * bflo(h1.x); a1 += w1 * bfhi(h1.x);
        a2 += w1 * bflo(h1.y); a3 += w1 * bfhi(h1.y);
        a4 += w1 * bflo(h1.z); a5 += w1 * bfhi(h1.z);
        a6 += w1 * bflo(h1.w); a7 += w1 * bfhi(h1.w);
    }

    // fold the 8 edge-groups (bits 3,4,5 of lane)
#pragma unroll
    for (int off = 8; off <= 32; off <<= 1) {
        a0 += __shfl_xor(a0, off, 64); a1 += __shfl_xor(a1, off, 64);
        a2 += __shfl_xor(a2, off, 64); a3 += __shfl_xor(a3, off, 64);
        a4 += __shfl_xor(a4, off, 64); a5 += __shfl_xor(a5, off, 64);
        a6 += __shfl_xor(a6, off, 64); a7 += __shfl_xor(a7, off, 64);
    }

    // perturbation: v = acc + sign(acc) * (r/max(||r||,eps)) * EPS  (fp32 noise)
    const float4* nz = (const float4*)(noise_k + (long)row * EMB);
    float4 n0 = nz[sub * 2];
    float4 n1 = nz[sub * 2 + 1];
    float ss = n0.x * n0.x + n0.y * n0.y + n0.z * n0.z + n0.w * n0.w
             + n1.x * n1.x + n1.y * n1.y + n1.z * n1.z + n1.w * n1.w;
    ss += __shfl_xor(ss, 1, 64);
    ss += __shfl_xor(ss, 2, 64);
    ss += __shfl_xor(ss, 4, 64);
    float s = EPS_F / fmaxf(sqrtf(ss), NORM_EPS_F);

    float v0 = a0 + ((a0 > 0.f) ? 1.f : ((a0 < 0.f) ? -1.f : 0.f)) * n0.x * s;
    float v1 = a1 + ((a1 > 0.f) ? 1.f : ((a1 < 0.f) ? -1.f : 0.f)) * n0.y * s;
    float v2 = a2 + ((a2 > 0.f) ? 1.f : ((a2 < 0.f) ? -1.f : 0.f)) * n0.z * s;
    float v3 = a3 + ((a3 > 0.f) ? 1.f : ((a3 < 0.f) ? -1.f : 0.f)) * n0.w * s;
    float v4 = a4 + ((a4 > 0.f) ? 1.f : ((a4 < 0.f) ? -1.f : 0.f)) * n1.x * s;
    float v5 = a5 + ((a5 > 0.f) ? 1.f : ((a5 < 0.f) ? -1.f : 0.f)) * n1.y * s;
    float v6 = a6 + ((a6 > 0.f) ? 1.f : ((a6 < 0.f) ? -1.f : 0.f)) * n1.z * s;
    float v7 = a7 + ((a7 > 0.f) ? 1.f : ((a7 < 0.f) ? -1.f : 0.f)) * n1.w * s;

    if (g == 0) {
        float4* po = (float4*)(out + (long)row * EMB);
        float4 f01 = make_float4(v0, v1, v2, v3);
        float4 f23 = make_float4(v4, v5, v6, v7);
        if (mode == 0) {
            po[sub * 2] = f01;
            po[sub * 2 + 1] = f23;
        } else if (mode == 1) {
            float4 o0 = po[sub * 2], o1 = po[sub * 2 + 1];
            o0.x += v0; o0.y += v1; o0.z += v2; o0.w += v3;
            o1.x += v4; o1.y += v5; o1.z += v6; o1.w += v7;
            po[sub * 2] = o0;
            po[sub * 2 + 1] = o1;
        } else {
            float4 o0 = po[sub * 2], o1 = po[sub * 2 + 1];
            o0.x = (o0.x + v0) * (1.f / 3.f); o0.y = (o0.y + v1) * (1.f / 3.f);
            o0.z = (o0.z + v2) * (1.f / 3.f); o0.w = (o0.w + v3) * (1.f / 3.f);
            o1.x = (o1.x + v4) * (1.f / 3.f); o1.y = (o1.y + v5) * (1.f / 3.f);
            o1.z = (o1.z + v6) * (1.f / 3.f); o1.w = (o1.w + v7) * (1.f / 3.f);
            po[sub * 2] = o0;
            po[sub * 2 + 1] = o1;
        }
        if (mode != 2) {
            uint4* ph = (uint4*)(x_out + (long)row * (EMB / 2));
            ph[sub] = make_uint4(pack2(v0, v1), pack2(v2, v3),
                                 pack2(v4, v5), pack2(v6, v7));
        }
    }
}

// ---------------- launch ----------------

extern "C" void kernel_launch(void* const* d_in, const int* in_sizes, int n_in,
                              void* d_out, int out_size, void* d_ws, size_t ws_size,
                              hipStream_t stream) {
    const float* user_emb = (const float*)d_in[0];
    const float* item_emb = (const float*)d_in[1];
    const int*   adj_rows = (const int*)d_in[2];
    const int*   adj_cols = (const int*)d_in[3];
    const float* adj_vals = (const float*)d_in[4];
    const float* noise    = (const float*)d_in[5];
    float* out = (float*)d_out;

    char* ws = (char*)d_ws;
    size_t off = 0;
    auto alloc = [&](size_t bytes) {
        char* p = ws + off;
        off += (bytes + 15) & ~size_t(15);
        return p;
    };
    int*   row_ptr     = (int*)alloc((N_NODES + 1) * sizeof(int));
    int*   gcursor     = (int*)alloc(NB * sizeof(int));
    int*   bucket_base = (int*)alloc(NB * sizeof(int));
    int2*  edges       = (int2*)alloc((size_t)NNZ * sizeof(int2));
    int2*  staging     = (int2*)alloc((size_t)NB * CAP * sizeof(int2));  // 43.2 MB
    // bf16 x buffers alias staging (staging dead after binB; xh_a written by
    // convert_kernel which runs after binB; xh_b first written by layer 0).
    uint* xh_a = (uint*)staging;                                   // 19.2 MB
    uint* xh_b = (uint*)((char*)staging + (size_t)N_NODES * EMB * 2);

    // ---- CSR build ----
    init_gcursor<<<3, 256, 0, stream>>>(gcursor);
    binA_kernel<<<BINA_GRID, 512, 0, stream>>>(adj_rows, adj_cols, adj_vals,
                                               gcursor, staging);
    bscan_kernel<<<1, 1024, 0, stream>>>(gcursor, bucket_base, row_ptr);
    binB_kernel<<<NB, 1024, 0, stream>>>(gcursor, bucket_base, staging, edges,
                                         row_ptr);

    // ---- fp32 -> bf16 convert (fused concat) ----
    convert_kernel<<<2048, 256, 0, stream>>>((const float4*)user_emb,
                                             (const float4*)item_emb, (uint2*)xh_a);

    // ---- 3 layers ----
    const int LGRID = (N_NODES + 3) / 4;
    const size_t NE = (size_t)N_NODES * EMB;
    spmm_layer_kernel<<<LGRID, 256, 0, stream>>>(xh_a, xh_b, row_ptr, edges,
                                                 noise + 0 * NE, out, 0);
    spmm_layer_kernel<<<LGRID, 256, 0, stream>>>(xh_b, xh_a, row_ptr, edges,
                                                 noise + 1 * NE, out, 1);
    spmm_layer_kernel<<<LGRID, 256, 0, stream>>>(xh_a, nullptr, row_ptr, edges,
                                                 noise + 2 * NE, out, 2);
}